// Round 1
// baseline (678.085 us; speedup 1.0000x reference)
//
#include <hip/hip_runtime.h>
#include <math.h>

typedef unsigned short u16;

#define BSZ 128
#define SEQL 128
#define DIM 768
#define FEAT 1024
#define WORDS_OUT_ELEMS (BSZ * FEAT * 126)  // 16,515,072

typedef __attribute__((ext_vector_type(8))) __bf16 bf16x8;
typedef __attribute__((ext_vector_type(4))) float f32x4;

__device__ __forceinline__ u16 f2bf(float x) {
  unsigned u = __float_as_uint(x);
  u += 0x7FFFu + ((u >> 16) & 1u);
  return (u16)(u >> 16);
}
__device__ __forceinline__ float bf2f(u16 s) {
  return __uint_as_float(((unsigned)s) << 16);
}

__device__ __forceinline__ void gld_lds16(const void* g, void* l) {
  __builtin_amdgcn_global_load_lds(
      (const __attribute__((address_space(1))) void*)g,
      (__attribute__((address_space(3))) void*)l, 16, 0, 0);
}

// ---------------- fp32 -> bf16 convert ----------------
__global__ __launch_bounds__(256) void cvt_bf16(const float* __restrict__ src,
                                                u16* __restrict__ dst, int n4) {
  int i = blockIdx.x * 256 + threadIdx.x;
  if (i >= n4) return;
  float4 v = ((const float4*)src)[i];
  ushort4 o;
  o.x = f2bf(v.x); o.y = f2bf(v.y); o.z = f2bf(v.z); o.w = f2bf(v.w);
  ((ushort4*)dst)[i] = o;
}

// ---------------- conv-as-GEMM: C[m,n] = relu(A_win[m,:KD] . W[n,:KD] + bias[n]) ----------------
// A: bf16 words (BSZ, SEQL, DIM) contiguous; row m -> (b = m/Lp, l = m%Lp), window start (b*SEQL+l)*DIM.
// W: bf16 (FEAT, KD) row-major (B^T layout). C: bf16 (M, FEAT).
__global__ __launch_bounds__(256) void gemm_bt(const u16* __restrict__ A,
                                               const u16* __restrict__ W,
                                               const float* __restrict__ bias,
                                               u16* __restrict__ C,
                                               int Lp, int KD) {
  __shared__ u16 As[128 * 64];
  __shared__ u16 Bs[128 * 64];
  const int tid = threadIdx.x;
  const int wave = tid >> 6;
  const int lane = tid & 63;
  const int tile_m = blockIdx.x;
  const int tile_n = blockIdx.y;

  // staging: each wave iteration covers 8 rows x 128B; lane -> (row = lr, 16B chunk lc)
  const int lr = lane >> 3;
  const int lcol = (lane & 7) * 8;  // element offset within row
  const u16* ag[4];
  const u16* bg[4];
  unsigned lofs[4];
#pragma unroll
  for (int i = 0; i < 4; ++i) {
    int rl = wave * 32 + i * 8 + lr;  // 0..127
    int m = tile_m * 128 + rl;
    int bb = m / Lp;
    int ll = m - bb * Lp;
    ag[i] = A + (size_t)(bb * SEQL + ll) * DIM + lcol;
    int n = tile_n * 128 + rl;
    bg[i] = W + (size_t)n * KD + lcol;
    lofs[i] = __builtin_amdgcn_readfirstlane((unsigned)((wave * 32 + i * 8) * 64));
  }

  f32x4 acc[4][4];
#pragma unroll
  for (int mi = 0; mi < 4; ++mi)
#pragma unroll
    for (int ni = 0; ni < 4; ++ni) acc[mi][ni] = 0.0f;

  const int wm = (wave & 1) * 64;
  const int wn = (wave >> 1) * 64;
  const int frow = lane & 15;
  const int fq = lane >> 4;

  for (int k0 = 0; k0 < KD; k0 += 64) {
#pragma unroll
    for (int i = 0; i < 4; ++i) gld_lds16(ag[i] + k0, &As[lofs[i]]);
#pragma unroll
    for (int i = 0; i < 4; ++i) gld_lds16(bg[i] + k0, &Bs[lofs[i]]);
    __syncthreads();
#pragma unroll
    for (int kc = 0; kc < 2; ++kc) {
      bf16x8 af[4], bfr[4];
#pragma unroll
      for (int mi = 0; mi < 4; ++mi)
        af[mi] = *(const bf16x8*)&As[(wm + mi * 16 + frow) * 64 + kc * 32 + fq * 8];
#pragma unroll
      for (int ni = 0; ni < 4; ++ni)
        bfr[ni] = *(const bf16x8*)&Bs[(wn + ni * 16 + frow) * 64 + kc * 32 + fq * 8];
#pragma unroll
      for (int mi = 0; mi < 4; ++mi)
#pragma unroll
        for (int ni = 0; ni < 4; ++ni)
          acc[mi][ni] = __builtin_amdgcn_mfma_f32_16x16x32_bf16(af[mi], bfr[ni],
                                                                acc[mi][ni], 0, 0, 0);
    }
    __syncthreads();
  }

  // epilogue: bias + relu, store bf16. C/D map: col = lane&15, row = (lane>>4)*4 + reg
  float bv[4];
#pragma unroll
  for (int ni = 0; ni < 4; ++ni) bv[ni] = bias[tile_n * 128 + wn + ni * 16 + frow];
#pragma unroll
  for (int mi = 0; mi < 4; ++mi) {
#pragma unroll
    for (int r = 0; r < 4; ++r) {
      int mg = tile_m * 128 + wm + mi * 16 + fq * 4 + r;
      size_t rowoff = (size_t)mg * FEAT + tile_n * 128 + wn;
#pragma unroll
      for (int ni = 0; ni < 4; ++ni) {
        float v = acc[mi][ni][r] + bv[ni];
        v = fmaxf(v, 0.0f);
        C[rowoff + ni * 16 + frow] = f2bf(v);
      }
    }
  }
}

__device__ __forceinline__ float4 load_bf4(const u16* p) {
  uint2 q = *(const uint2*)p;
  float4 r;
  r.x = __uint_as_float((q.x & 0xFFFFu) << 16);
  r.y = __uint_as_float(q.x & 0xFFFF0000u);
  r.z = __uint_as_float((q.y & 0xFFFFu) << 16);
  r.w = __uint_as_float(q.y & 0xFFFF0000u);
  return r;
}

// ---------------- combine (max over branches) + L2 norm over FEAT + transposed write ----------------
// a: (BSZ,127,FEAT) b: (BSZ,126,FEAT) c: (BSZ,125,FEAT), all bf16.
// out[b, f, l] for l in [0,126). grid (9, BSZ), 14 l's per block.
__global__ __launch_bounds__(256) void combine_norm(const u16* __restrict__ a,
                                                    const u16* __restrict__ b,
                                                    const u16* __restrict__ c,
                                                    float* __restrict__ out) {
  __shared__ float comb[14 * 1024];
  __shared__ float red[14 * 4];
  __shared__ float inv[14];
  const int tid = threadIdx.x;
  const int wave = tid >> 6, lane = tid & 63;
  const int l0 = blockIdx.x * 14;
  const int bb = blockIdx.y;
  const int f0 = tid * 4;

  float part[14];
#pragma unroll
  for (int l = 0; l < 14; ++l) {
    int lg = l0 + l;
    float4 v = load_bf4(a + (size_t)(bb * 127 + lg) * 1024 + f0);
    if (lg < 125) {  // b_ contributes for l <= 124
      float4 vb = load_bf4(b + (size_t)(bb * 126 + lg) * 1024 + f0);
      v.x = fmaxf(v.x, vb.x); v.y = fmaxf(v.y, vb.y);
      v.z = fmaxf(v.z, vb.z); v.w = fmaxf(v.w, vb.w);
    }
    if (lg < 124) {  // c contributes for l <= 123
      float4 vc = load_bf4(c + (size_t)(bb * 125 + lg) * 1024 + f0);
      v.x = fmaxf(v.x, vc.x); v.y = fmaxf(v.y, vc.y);
      v.z = fmaxf(v.z, vc.z); v.w = fmaxf(v.w, vc.w);
    }
    comb[l * 1024 + f0 + 0] = v.x;
    comb[l * 1024 + f0 + 1] = v.y;
    comb[l * 1024 + f0 + 2] = v.z;
    comb[l * 1024 + f0 + 3] = v.w;
    part[l] = v.x * v.x + v.y * v.y + v.z * v.z + v.w * v.w;
  }
#pragma unroll
  for (int l = 0; l < 14; ++l) {
    float v = part[l];
    for (int off = 32; off > 0; off >>= 1) v += __shfl_down(v, off);
    if (lane == 0) red[l * 4 + wave] = v;
  }
  __syncthreads();
  if (tid < 14) {
    float s = red[tid * 4] + red[tid * 4 + 1] + red[tid * 4 + 2] + red[tid * 4 + 3];
    inv[tid] = 1.0f / fmaxf(sqrtf(s), 1e-12f);
  }
  __syncthreads();

  const size_t ob = (size_t)bb * FEAT * 126;
#pragma unroll
  for (int it = 0; it < 4; ++it) {
    int f = tid + it * 256;
    float* po = out + ob + (size_t)f * 126 + l0;
#pragma unroll
    for (int j = 0; j < 7; ++j) {
      float2 w;
      w.x = comb[(2 * j) * 1024 + f] * inv[2 * j];
      w.y = comb[(2 * j + 1) * 1024 + f] * inv[2 * j + 1];
      *(float2*)(po + 2 * j) = w;
    }
  }
}

// ---------------- sentence head: l2norm(se @ Wp^T + bp) ----------------
__global__ __launch_bounds__(256) void sent_head(const float* __restrict__ se,
                                                 const float* __restrict__ Wp,
                                                 const float* __restrict__ bp,
                                                 float* __restrict__ out) {
  __shared__ float srow[768];
  __shared__ float ov[1024];
  __shared__ float red[4];
  const int b = blockIdx.x, tid = threadIdx.x;
  for (int i = tid; i < 768; i += 256) srow[i] = se[b * 768 + i];
  __syncthreads();
  float ss = 0.f;
#pragma unroll
  for (int it = 0; it < 4; ++it) {
    int f = tid + it * 256;
    const float4* w = (const float4*)(Wp + (size_t)f * 768);
    float acc = 0.f;
    for (int j = 0; j < 192; ++j) {
      float4 wv = w[j];
      float4 sv = *(const float4*)&srow[j * 4];
      acc += wv.x * sv.x + wv.y * sv.y + wv.z * sv.z + wv.w * sv.w;
    }
    acc += bp[f];
    ov[f] = acc;
    ss += acc * acc;
  }
  const int lane = tid & 63, wave = tid >> 6;
  for (int off = 32; off > 0; off >>= 1) ss += __shfl_down(ss, off);
  if (lane == 0) red[wave] = ss;
  __syncthreads();
  float tot = red[0] + red[1] + red[2] + red[3];
  float inv = 1.0f / fmaxf(sqrtf(tot), 1e-12f);
  for (int it = 0; it < 4; ++it) {
    int f = tid + it * 256;
    out[WORDS_OUT_ELEMS + (size_t)b * 1024 + f] = ov[f] * inv;
  }
}

extern "C" void kernel_launch(void* const* d_in, const int* in_sizes, int n_in,
                              void* d_out, int out_size, void* d_ws, size_t ws_size,
                              hipStream_t stream) {
  const float* words = (const float*)d_in[0];
  const float* sent = (const float*)d_in[1];
  const float* W2 = (const float*)d_in[2];
  const float* b2 = (const float*)d_in[3];
  const float* W3 = (const float*)d_in[4];
  const float* b3 = (const float*)d_in[5];
  const float* W4 = (const float*)d_in[6];
  const float* b4 = (const float*)d_in[7];
  const float* Wp = (const float*)d_in[8];
  const float* bp = (const float*)d_in[9];
  float* out = (float*)d_out;

  char* ws = (char*)d_ws;
  // layout (bytes):
  u16* A_bf = (u16*)(ws + 0);            // 12,582,912 elems -> 25,165,824 B
  u16* W2_bf = (u16*)(ws + 25165824);    // 1,572,864 -> 3,145,728 B
  u16* W3_bf = (u16*)(ws + 28311552);    // 2,359,296 -> 4,718,592 B
  u16* W4_bf = (u16*)(ws + 33030144);    // 3,145,728 -> 6,291,456 B
  u16* a_out = (u16*)(ws + 39321600);    // 16256*1024 bf16
  u16* b_out = (u16*)(ws + 72613888);    // 16128*1024 bf16
  u16* c_out = (u16*)(ws + 105644032);   // 16000*1024 bf16  (end 138,412,032 B)

  cvt_bf16<<<12288, 256, 0, stream>>>(words, A_bf, 3145728);
  cvt_bf16<<<1536, 256, 0, stream>>>(W2, W2_bf, 393216);
  cvt_bf16<<<2304, 256, 0, stream>>>(W3, W3_bf, 589824);
  cvt_bf16<<<3072, 256, 0, stream>>>(W4, W4_bf, 786432);

  gemm_bt<<<dim3(127, 8), 256, 0, stream>>>(A_bf, W2_bf, b2, a_out, 127, 1536);
  gemm_bt<<<dim3(126, 8), 256, 0, stream>>>(A_bf, W3_bf, b3, b_out, 126, 2304);
  gemm_bt<<<dim3(125, 8), 256, 0, stream>>>(A_bf, W4_bf, b4, c_out, 125, 3072);

  combine_norm<<<dim3(9, BSZ), 256, 0, stream>>>(a_out, b_out, c_out, out);
  sent_head<<<BSZ, 256, 0, stream>>>(sent, Wp, bp, out);
}

// Round 2
// 649.234 us; speedup vs baseline: 1.0444x; 1.0444x over previous
//
#include <hip/hip_runtime.h>
#include <math.h>

typedef unsigned short u16;

#define BSZ 128
#define SEQL 128
#define DIM 768
#define FEAT 1024
#define WORDS_OUT_ELEMS (BSZ * FEAT * 126)  // 16,515,072

typedef __attribute__((ext_vector_type(8))) __bf16 bf16x8;
typedef __attribute__((ext_vector_type(4))) float f32x4;

__device__ __forceinline__ u16 f2bf(float x) {
  unsigned u = __float_as_uint(x);
  u += 0x7FFFu + ((u >> 16) & 1u);
  return (u16)(u >> 16);
}

__device__ __forceinline__ void gld_lds16(const void* g, void* l) {
  __builtin_amdgcn_global_load_lds(
      (const __attribute__((address_space(1))) void*)g,
      (__attribute__((address_space(3))) void*)l, 16, 0, 0);
}

// ---------------- fp32 -> bf16 convert ----------------
__global__ __launch_bounds__(256) void cvt_bf16(const float* __restrict__ src,
                                                u16* __restrict__ dst, int n4) {
  int i = blockIdx.x * 256 + threadIdx.x;
  if (i >= n4) return;
  float4 v = ((const float4*)src)[i];
  ushort4 o;
  o.x = f2bf(v.x); o.y = f2bf(v.y); o.z = f2bf(v.z); o.w = f2bf(v.w);
  ((ushort4*)dst)[i] = o;
}

// ---------------- conv-as-GEMM: C[m,n] = relu(A_win[m,:KD] . W[n,:KD] + bias[n]) ----------------
// A: bf16 words (BSZ, SEQL, DIM) contiguous; row m -> (b = m/Lp, l = m%Lp), window start (b*SEQL+l)*DIM.
// W: bf16 (FEAT, KD) row-major (B^T layout). C: bf16 (M, FEAT).
// LDS XOR swizzle: global chunk (row r, 16B-chunk c) is stored in LDS slot (r, c ^ (r&7));
// legal because global_load_lds only fixes the LDS side (base + lane*16), source addr is per-lane.
// grid: blockIdx.x = tile_n (8, fast -> one n-column per XCD, B tile L2-resident),
//       blockIdx.y = tile_m.
__global__ __launch_bounds__(256) void gemm_bt(const u16* __restrict__ A,
                                               const u16* __restrict__ W,
                                               const float* __restrict__ bias,
                                               u16* __restrict__ C,
                                               int Lp, int KD) {
  __shared__ u16 As[128 * 64];
  __shared__ u16 Bs[128 * 64];
  const int tid = threadIdx.x;
  const int wave = tid >> 6;
  const int lane = tid & 63;
  const int tile_n = blockIdx.x;
  const int tile_m = blockIdx.y;

  // staging: each wave iteration covers 8 rows x 128B; lane -> (row lr, swizzled src chunk)
  const int lr = lane >> 3;
  const int lc = lane & 7;
  const int lcol = (lc ^ (lr & 7)) * 8;  // XOR-swizzled source element offset within row
  const u16* ag[4];
  const u16* bg[4];
  unsigned lofs[4];
#pragma unroll
  for (int i = 0; i < 4; ++i) {
    int rl = wave * 32 + i * 8 + lr;  // 0..127
    int m = tile_m * 128 + rl;
    int bb = m / Lp;
    int ll = m - bb * Lp;
    ag[i] = A + (size_t)(bb * SEQL + ll) * DIM + lcol;
    int n = tile_n * 128 + rl;
    bg[i] = W + (size_t)n * KD + lcol;
    lofs[i] = __builtin_amdgcn_readfirstlane((unsigned)((wave * 32 + i * 8) * 64));
  }

  f32x4 acc[4][4];
#pragma unroll
  for (int mi = 0; mi < 4; ++mi)
#pragma unroll
    for (int ni = 0; ni < 4; ++ni) acc[mi][ni] = 0.0f;

  const int wm = (wave & 1) * 64;
  const int wn = (wave >> 1) * 64;
  const int frow = lane & 15;
  const int fq = lane >> 4;
  const int fsw = frow & 7;  // row-dependent XOR for fragment reads

  for (int k0 = 0; k0 < KD; k0 += 64) {
#pragma unroll
    for (int i = 0; i < 4; ++i) gld_lds16(ag[i] + k0, &As[lofs[i]]);
#pragma unroll
    for (int i = 0; i < 4; ++i) gld_lds16(bg[i] + k0, &Bs[lofs[i]]);
    __syncthreads();
#pragma unroll
    for (int kc = 0; kc < 2; ++kc) {
      const int csw = ((kc * 4 + fq) ^ fsw) * 8;  // swizzled chunk offset
      bf16x8 af[4], bfr[4];
#pragma unroll
      for (int mi = 0; mi < 4; ++mi)
        af[mi] = *(const bf16x8*)&As[(wm + mi * 16 + frow) * 64 + csw];
#pragma unroll
      for (int ni = 0; ni < 4; ++ni)
        bfr[ni] = *(const bf16x8*)&Bs[(wn + ni * 16 + frow) * 64 + csw];
#pragma unroll
      for (int mi = 0; mi < 4; ++mi)
#pragma unroll
        for (int ni = 0; ni < 4; ++ni)
          acc[mi][ni] = __builtin_amdgcn_mfma_f32_16x16x32_bf16(af[mi], bfr[ni],
                                                                acc[mi][ni], 0, 0, 0);
    }
    __syncthreads();
  }

  // epilogue: bias + relu, store bf16. C/D map: col = lane&15, row = (lane>>4)*4 + reg
  float bv[4];
#pragma unroll
  for (int ni = 0; ni < 4; ++ni) bv[ni] = bias[tile_n * 128 + wn + ni * 16 + frow];
#pragma unroll
  for (int mi = 0; mi < 4; ++mi) {
#pragma unroll
    for (int r = 0; r < 4; ++r) {
      int mg = tile_m * 128 + wm + mi * 16 + fq * 4 + r;
      size_t rowoff = (size_t)mg * FEAT + tile_n * 128 + wn;
#pragma unroll
      for (int ni = 0; ni < 4; ++ni) {
        float v = acc[mi][ni][r] + bv[ni];
        v = fmaxf(v, 0.0f);
        C[rowoff + ni * 16 + frow] = f2bf(v);
      }
    }
  }
}

__device__ __forceinline__ float4 load_bf4(const u16* p) {
  uint2 q = *(const uint2*)p;
  float4 r;
  r.x = __uint_as_float((q.x & 0xFFFFu) << 16);
  r.y = __uint_as_float(q.x & 0xFFFF0000u);
  r.z = __uint_as_float((q.y & 0xFFFFu) << 16);
  r.w = __uint_as_float(q.y & 0xFFFF0000u);
  return r;
}

// ---------------- combine (max over branches) + L2 norm over FEAT + transposed write ----------------
// a: (BSZ,127,FEAT) b: (BSZ,126,FEAT) c: (BSZ,125,FEAT), all bf16.
// out[b, f, l] for l in [0,126). grid (9, BSZ), 14 l's per block.
__global__ __launch_bounds__(256) void combine_norm(const u16* __restrict__ a,
                                                    const u16* __restrict__ b,
                                                    const u16* __restrict__ c,
                                                    float* __restrict__ out) {
  __shared__ float comb[14 * 1024];
  __shared__ float red[14 * 4];
  __shared__ float inv[14];
  const int tid = threadIdx.x;
  const int wave = tid >> 6, lane = tid & 63;
  const int l0 = blockIdx.x * 14;
  const int bb = blockIdx.y;
  const int f0 = tid * 4;

  float part[14];
#pragma unroll
  for (int l = 0; l < 14; ++l) {
    int lg = l0 + l;
    float4 v = load_bf4(a + (size_t)(bb * 127 + lg) * 1024 + f0);
    if (lg < 125) {  // b_ contributes for l <= 124
      float4 vb = load_bf4(b + (size_t)(bb * 126 + lg) * 1024 + f0);
      v.x = fmaxf(v.x, vb.x); v.y = fmaxf(v.y, vb.y);
      v.z = fmaxf(v.z, vb.z); v.w = fmaxf(v.w, vb.w);
    }
    if (lg < 124) {  // c contributes for l <= 123
      float4 vc = load_bf4(c + (size_t)(bb * 125 + lg) * 1024 + f0);
      v.x = fmaxf(v.x, vc.x); v.y = fmaxf(v.y, vc.y);
      v.z = fmaxf(v.z, vc.z); v.w = fmaxf(v.w, vc.w);
    }
    comb[l * 1024 + f0 + 0] = v.x;
    comb[l * 1024 + f0 + 1] = v.y;
    comb[l * 1024 + f0 + 2] = v.z;
    comb[l * 1024 + f0 + 3] = v.w;
    part[l] = v.x * v.x + v.y * v.y + v.z * v.z + v.w * v.w;
  }
#pragma unroll
  for (int l = 0; l < 14; ++l) {
    float v = part[l];
    for (int off = 32; off > 0; off >>= 1) v += __shfl_down(v, off);
    if (lane == 0) red[l * 4 + wave] = v;
  }
  __syncthreads();
  if (tid < 14) {
    float s = red[tid * 4] + red[tid * 4 + 1] + red[tid * 4 + 2] + red[tid * 4 + 3];
    inv[tid] = 1.0f / fmaxf(sqrtf(s), 1e-12f);
  }
  __syncthreads();

  const size_t ob = (size_t)bb * FEAT * 126;
#pragma unroll
  for (int it = 0; it < 4; ++it) {
    int f = tid + it * 256;
    float* po = out + ob + (size_t)f * 126 + l0;
#pragma unroll
    for (int j = 0; j < 7; ++j) {
      float2 w;
      w.x = comb[(2 * j) * 1024 + f] * inv[2 * j];
      w.y = comb[(2 * j + 1) * 1024 + f] * inv[2 * j + 1];
      *(float2*)(po + 2 * j) = w;
    }
  }
}

// ---------------- sentence head: l2norm(se @ Wp^T + bp) ----------------
__global__ __launch_bounds__(256) void sent_head(const float* __restrict__ se,
                                                 const float* __restrict__ Wp,
                                                 const float* __restrict__ bp,
                                                 float* __restrict__ out) {
  __shared__ float srow[768];
  __shared__ float ov[1024];
  __shared__ float red[4];
  const int b = blockIdx.x, tid = threadIdx.x;
  for (int i = tid; i < 768; i += 256) srow[i] = se[b * 768 + i];
  __syncthreads();
  float ss = 0.f;
#pragma unroll
  for (int it = 0; it < 4; ++it) {
    int f = tid + it * 256;
    const float4* w = (const float4*)(Wp + (size_t)f * 768);
    float acc = 0.f;
    for (int j = 0; j < 192; ++j) {
      float4 wv = w[j];
      float4 sv = *(const float4*)&srow[j * 4];
      acc += wv.x * sv.x + wv.y * sv.y + wv.z * sv.z + wv.w * sv.w;
    }
    acc += bp[f];
    ov[f] = acc;
    ss += acc * acc;
  }
  const int lane = tid & 63, wave = tid >> 6;
  for (int off = 32; off > 0; off >>= 1) ss += __shfl_down(ss, off);
  if (lane == 0) red[wave] = ss;
  __syncthreads();
  float tot = red[0] + red[1] + red[2] + red[3];
  float inv = 1.0f / fmaxf(sqrtf(tot), 1e-12f);
  for (int it = 0; it < 4; ++it) {
    int f = tid + it * 256;
    out[WORDS_OUT_ELEMS + (size_t)b * 1024 + f] = ov[f] * inv;
  }
}

extern "C" void kernel_launch(void* const* d_in, const int* in_sizes, int n_in,
                              void* d_out, int out_size, void* d_ws, size_t ws_size,
                              hipStream_t stream) {
  const float* words = (const float*)d_in[0];
  const float* sent = (const float*)d_in[1];
  const float* W2 = (const float*)d_in[2];
  const float* b2 = (const float*)d_in[3];
  const float* W3 = (const float*)d_in[4];
  const float* b3 = (const float*)d_in[5];
  const float* W4 = (const float*)d_in[6];
  const float* b4 = (const float*)d_in[7];
  const float* Wp = (const float*)d_in[8];
  const float* bp = (const float*)d_in[9];
  float* out = (float*)d_out;

  char* ws = (char*)d_ws;
  // layout (bytes):
  u16* A_bf = (u16*)(ws + 0);            // 12,582,912 elems -> 25,165,824 B
  u16* W2_bf = (u16*)(ws + 25165824);    // 1,572,864 -> 3,145,728 B
  u16* W3_bf = (u16*)(ws + 28311552);    // 2,359,296 -> 4,718,592 B
  u16* W4_bf = (u16*)(ws + 33030144);    // 3,145,728 -> 6,291,456 B
  u16* a_out = (u16*)(ws + 39321600);    // 16256*1024 bf16
  u16* b_out = (u16*)(ws + 72613888);    // 16128*1024 bf16
  u16* c_out = (u16*)(ws + 105644032);   // 16000*1024 bf16  (end 138,412,032 B)

  cvt_bf16<<<12288, 256, 0, stream>>>(words, A_bf, 3145728);
  cvt_bf16<<<1536, 256, 0, stream>>>(W2, W2_bf, 393216);
  cvt_bf16<<<2304, 256, 0, stream>>>(W3, W3_bf, 589824);
  cvt_bf16<<<3072, 256, 0, stream>>>(W4, W4_bf, 786432);

  // grid: x = tile_n (8, fast-varying -> one n-column per XCD), y = tile_m
  gemm_bt<<<dim3(8, 127), 256, 0, stream>>>(A_bf, W2_bf, b2, a_out, 127, 1536);
  gemm_bt<<<dim3(8, 126), 256, 0, stream>>>(A_bf, W3_bf, b3, b_out, 126, 2304);
  gemm_bt<<<dim3(8, 125), 256, 0, stream>>>(A_bf, W4_bf, b4, c_out, 125, 3072);

  combine_norm<<<dim3(9, BSZ), 256, 0, stream>>>(a_out, b_out, c_out, out);
  sent_head<<<BSZ, 256, 0, stream>>>(sent, Wp, bp, out);
}

// Round 3
// 584.923 us; speedup vs baseline: 1.1593x; 1.1099x over previous
//
#include <hip/hip_runtime.h>
#include <math.h>

typedef unsigned short u16;

#define BSZ 128
#define SEQL 128
#define DIM 768
#define FEAT 1024
#define WORDS_OUT_ELEMS (BSZ * FEAT * 126)  // 16,515,072

typedef __attribute__((ext_vector_type(8))) __bf16 bf16x8;
typedef __attribute__((ext_vector_type(4))) float f32x4;

__device__ __forceinline__ u16 f2bf(float x) {
  unsigned u = __float_as_uint(x);
  u += 0x7FFFu + ((u >> 16) & 1u);
  return (u16)(u >> 16);
}

__device__ __forceinline__ void gld_lds16(const void* g, void* l) {
  __builtin_amdgcn_global_load_lds(
      (const __attribute__((address_space(1))) void*)g,
      (__attribute__((address_space(3))) void*)l, 16, 0, 0);
}

// ---------------- fused fp32 -> bf16 convert (words + W2 + W3 + W4 in one dispatch) ----------------
#define N4_WORDS 3145728
#define N4_W2 393216
#define N4_W3 589824
#define N4_W4 786432
#define N4_TOTAL (N4_WORDS + N4_W2 + N4_W3 + N4_W4)  // 4,915,200

__global__ __launch_bounds__(256) void cvt_all(const float* __restrict__ words,
                                               const float* __restrict__ W2,
                                               const float* __restrict__ W3,
                                               const float* __restrict__ W4,
                                               u16* __restrict__ dA, u16* __restrict__ d2,
                                               u16* __restrict__ d3, u16* __restrict__ d4) {
  int i = blockIdx.x * 256 + threadIdx.x;
  if (i >= N4_TOTAL) return;
  const float* src;
  u16* dst;
  int j = i;
  if (j < N4_WORDS) {
    src = words; dst = dA;
  } else if ((j -= N4_WORDS) < N4_W2) {
    src = W2; dst = d2;
  } else if ((j -= N4_W2) < N4_W3) {
    src = W3; dst = d3;
  } else {
    j -= N4_W3; src = W4; dst = d4;
  }
  float4 v = ((const float4*)src)[j];
  ushort4 o;
  o.x = f2bf(v.x); o.y = f2bf(v.y); o.z = f2bf(v.z); o.w = f2bf(v.w);
  ((ushort4*)dst)[j] = o;
}

// ---------------- fused conv-as-GEMM, all 3 branches in one dispatch ----------------
// z = branch (0:K=2, 1:K=3, 2:K=4). C[m,n] = relu(A_win[m,:KD] . W[n,:KD] + bias[n]).
// A row m -> (b = m/Lp, l = m%Lp), window start (b*SEQL+l)*DIM, contiguous KD elems.
// LDS XOR swizzle: global chunk (row r, 16B-chunk c) stored in LDS slot (r, c ^ (r&7)).
// C stored with PERMUTED n within each 64-col wave chunk: stored col = frow*4+ni for
// actual col = ni*16+frow  -> each thread stores 4 consecutive bf16 (8 B) per (mi,r).
// combine_norm de-permutes. Max/L2-norm are permutation-invariant.
__global__ __launch_bounds__(256) void gemm_fused(const u16* __restrict__ A,
                                                  const u16* __restrict__ W2,
                                                  const u16* __restrict__ W3,
                                                  const u16* __restrict__ W4,
                                                  const float* __restrict__ b2,
                                                  const float* __restrict__ b3,
                                                  const float* __restrict__ b4,
                                                  u16* __restrict__ Ca,
                                                  u16* __restrict__ Cb,
                                                  u16* __restrict__ Cc) {
  __shared__ u16 As[128 * 64];
  __shared__ u16 Bs[128 * 64];
  const int z = blockIdx.z;
  const int Lp = 127 - z;            // 127, 126, 125
  const int KD = 1536 + z * 768;     // 1536, 2304, 3072
  const int tile_n = blockIdx.x;
  const int tile_m = blockIdx.y;
  if (tile_m >= Lp) return;  // uniform early-exit before any barrier

  const u16* W = (z == 0) ? W2 : (z == 1) ? W3 : W4;
  const float* bias = (z == 0) ? b2 : (z == 1) ? b3 : b4;
  u16* C = (z == 0) ? Ca : (z == 1) ? Cb : Cc;

  const int tid = threadIdx.x;
  const int wave = tid >> 6;
  const int lane = tid & 63;

  // staging: each wave iteration covers 8 rows x 128B; lane -> (row lr, swizzled src chunk)
  const int lr = lane >> 3;
  const int lc = lane & 7;
  const int lcol = (lc ^ (lr & 7)) * 8;  // XOR-swizzled source element offset within row
  const u16* ag[4];
  const u16* bg[4];
  unsigned lofs[4];
#pragma unroll
  for (int i = 0; i < 4; ++i) {
    int rl = wave * 32 + i * 8 + lr;  // 0..127
    int m = tile_m * 128 + rl;
    int bb = m / Lp;
    int ll = m - bb * Lp;
    ag[i] = A + (size_t)(bb * SEQL + ll) * DIM + lcol;
    int n = tile_n * 128 + rl;
    bg[i] = W + (size_t)n * KD + lcol;
    lofs[i] = __builtin_amdgcn_readfirstlane((unsigned)((wave * 32 + i * 8) * 64));
  }

  f32x4 acc[4][4];
#pragma unroll
  for (int mi = 0; mi < 4; ++mi)
#pragma unroll
    for (int ni = 0; ni < 4; ++ni) acc[mi][ni] = 0.0f;

  const int wm = (wave & 1) * 64;
  const int wn = (wave >> 1) * 64;
  const int frow = lane & 15;
  const int fq = lane >> 4;
  const int fsw = frow & 7;  // row-dependent XOR for fragment reads

  for (int k0 = 0; k0 < KD; k0 += 64) {
#pragma unroll
    for (int i = 0; i < 4; ++i) gld_lds16(ag[i] + k0, &As[lofs[i]]);
#pragma unroll
    for (int i = 0; i < 4; ++i) gld_lds16(bg[i] + k0, &Bs[lofs[i]]);
    __syncthreads();
#pragma unroll
    for (int kc = 0; kc < 2; ++kc) {
      const int csw = ((kc * 4 + fq) ^ fsw) * 8;  // swizzled chunk offset
      bf16x8 af[4], bfr[4];
#pragma unroll
      for (int mi = 0; mi < 4; ++mi)
        af[mi] = *(const bf16x8*)&As[(wm + mi * 16 + frow) * 64 + csw];
#pragma unroll
      for (int ni = 0; ni < 4; ++ni)
        bfr[ni] = *(const bf16x8*)&Bs[(wn + ni * 16 + frow) * 64 + csw];
#pragma unroll
      for (int mi = 0; mi < 4; ++mi)
#pragma unroll
        for (int ni = 0; ni < 4; ++ni)
          acc[mi][ni] = __builtin_amdgcn_mfma_f32_16x16x32_bf16(af[mi], bfr[ni],
                                                                acc[mi][ni], 0, 0, 0);
    }
    __syncthreads();
  }

  // epilogue: bias + relu, permuted-packed bf16 stores (8 B / thread / (mi,r)).
  // C/D map: actual col = ni*16+frow (lane&15), row = fq*4 + reg.
  float bv[4];
#pragma unroll
  for (int ni = 0; ni < 4; ++ni) bv[ni] = bias[tile_n * 128 + wn + ni * 16 + frow];
#pragma unroll
  for (int mi = 0; mi < 4; ++mi) {
#pragma unroll
    for (int r = 0; r < 4; ++r) {
      int mg = tile_m * 128 + wm + mi * 16 + fq * 4 + r;
      ushort4 hs;
      {
        float v0 = fmaxf(acc[mi][0][r] + bv[0], 0.0f);
        float v1 = fmaxf(acc[mi][1][r] + bv[1], 0.0f);
        float v2 = fmaxf(acc[mi][2][r] + bv[2], 0.0f);
        float v3 = fmaxf(acc[mi][3][r] + bv[3], 0.0f);
        hs.x = f2bf(v0); hs.y = f2bf(v1); hs.z = f2bf(v2); hs.w = f2bf(v3);
      }
      *(ushort4*)(C + (size_t)mg * FEAT + tile_n * 128 + wn + frow * 4) = hs;
    }
  }
}

__device__ __forceinline__ float4 load_bf4(const u16* p) {
  uint2 q = *(const uint2*)p;
  float4 r;
  r.x = __uint_as_float((q.x & 0xFFFFu) << 16);
  r.y = __uint_as_float(q.x & 0xFFFF0000u);
  r.z = __uint_as_float((q.y & 0xFFFFu) << 16);
  r.w = __uint_as_float(q.y & 0xFFFF0000u);
  return r;
}

// ---------------- combine (max over branches) + L2 norm over FEAT + transposed write ----------------
// a: (BSZ,127,FEAT) b: (BSZ,126,FEAT) c: (BSZ,125,FEAT), bf16, PERMUTED col layout:
// within each 64-col chunk, stored index s holds actual col (s&3)*16 + (s>>2).
// Thread tid reads stored cols tid*4..tid*4+3 => chunk = tid>>4, frow = tid&15,
// actual cols = chunk*64 + ni*16 + frow (ni=0..3). De-permute when scattering into LDS.
// out[b, f, l] for l in [0,126). grid (9, BSZ), 14 l's per block.
__global__ __launch_bounds__(256) void combine_norm(const u16* __restrict__ a,
                                                    const u16* __restrict__ b,
                                                    const u16* __restrict__ c,
                                                    float* __restrict__ out) {
  __shared__ float comb[14 * 1024];
  __shared__ float red[14 * 4];
  __shared__ float inv[14];
  const int tid = threadIdx.x;
  const int wave = tid >> 6, lane = tid & 63;
  const int l0 = blockIdx.x * 14;
  const int bb = blockIdx.y;
  const int f0 = tid * 4;                       // stored (permuted) index
  const int chunk = tid >> 4, frow = tid & 15;  // de-permute params
  const int fbase = chunk * 64 + frow;          // actual col for ni=0 (then +16 per ni)

  float part[14];
#pragma unroll
  for (int l = 0; l < 14; ++l) {
    int lg = l0 + l;
    float4 v = load_bf4(a + (size_t)(bb * 127 + lg) * 1024 + f0);
    if (lg < 125) {  // b_ contributes for l <= 124
      float4 vb = load_bf4(b + (size_t)(bb * 126 + lg) * 1024 + f0);
      v.x = fmaxf(v.x, vb.x); v.y = fmaxf(v.y, vb.y);
      v.z = fmaxf(v.z, vb.z); v.w = fmaxf(v.w, vb.w);
    }
    if (lg < 124) {  // c contributes for l <= 123
      float4 vc = load_bf4(c + (size_t)(bb * 125 + lg) * 1024 + f0);
      v.x = fmaxf(v.x, vc.x); v.y = fmaxf(v.y, vc.y);
      v.z = fmaxf(v.z, vc.z); v.w = fmaxf(v.w, vc.w);
    }
    // de-permuted scatter into LDS (actual feature positions)
    comb[l * 1024 + fbase + 0] = v.x;
    comb[l * 1024 + fbase + 16] = v.y;
    comb[l * 1024 + fbase + 32] = v.z;
    comb[l * 1024 + fbase + 48] = v.w;
    part[l] = v.x * v.x + v.y * v.y + v.z * v.z + v.w * v.w;  // perm-invariant
  }
#pragma unroll
  for (int l = 0; l < 14; ++l) {
    float v = part[l];
    for (int off = 32; off > 0; off >>= 1) v += __shfl_down(v, off);
    if (lane == 0) red[l * 4 + wave] = v;
  }
  __syncthreads();
  if (tid < 14) {
    float s = red[tid * 4] + red[tid * 4 + 1] + red[tid * 4 + 2] + red[tid * 4 + 3];
    inv[tid] = 1.0f / fmaxf(sqrtf(s), 1e-12f);
  }
  __syncthreads();

  const size_t ob = (size_t)bb * FEAT * 126;
#pragma unroll
  for (int it = 0; it < 4; ++it) {
    int f = tid + it * 256;
    float* po = out + ob + (size_t)f * 126 + l0;
#pragma unroll
    for (int j = 0; j < 7; ++j) {
      float2 w;
      w.x = comb[(2 * j) * 1024 + f] * inv[2 * j];
      w.y = comb[(2 * j + 1) * 1024 + f] * inv[2 * j + 1];
      *(float2*)(po + 2 * j) = w;
    }
  }
}

// ---------------- sentence head: l2norm(se @ Wp^T + bp) ----------------
__global__ __launch_bounds__(256) void sent_head(const float* __restrict__ se,
                                                 const float* __restrict__ Wp,
                                                 const float* __restrict__ bp,
                                                 float* __restrict__ out) {
  __shared__ float srow[768];
  __shared__ float ov[1024];
  __shared__ float red[4];
  const int b = blockIdx.x, tid = threadIdx.x;
  for (int i = tid; i < 768; i += 256) srow[i] = se[b * 768 + i];
  __syncthreads();
  float ss = 0.f;
#pragma unroll
  for (int it = 0; it < 4; ++it) {
    int f = tid + it * 256;
    const float4* w = (const float4*)(Wp + (size_t)f * 768);
    float acc = 0.f;
    for (int j = 0; j < 192; ++j) {
      float4 wv = w[j];
      float4 sv = *(const float4*)&srow[j * 4];
      acc += wv.x * sv.x + wv.y * sv.y + wv.z * sv.z + wv.w * sv.w;
    }
    acc += bp[f];
    ov[f] = acc;
    ss += acc * acc;
  }
  const int lane = tid & 63, wave = tid >> 6;
  for (int off = 32; off > 0; off >>= 1) ss += __shfl_down(ss, off);
  if (lane == 0) red[wave] = ss;
  __syncthreads();
  float tot = red[0] + red[1] + red[2] + red[3];
  float inv = 1.0f / fmaxf(sqrtf(tot), 1e-12f);
  for (int it = 0; it < 4; ++it) {
    int f = tid + it * 256;
    out[WORDS_OUT_ELEMS + (size_t)b * 1024 + f] = ov[f] * inv;
  }
}

extern "C" void kernel_launch(void* const* d_in, const int* in_sizes, int n_in,
                              void* d_out, int out_size, void* d_ws, size_t ws_size,
                              hipStream_t stream) {
  const float* words = (const float*)d_in[0];
  const float* sent = (const float*)d_in[1];
  const float* W2 = (const float*)d_in[2];
  const float* b2 = (const float*)d_in[3];
  const float* W3 = (const float*)d_in[4];
  const float* b3 = (const float*)d_in[5];
  const float* W4 = (const float*)d_in[6];
  const float* b4 = (const float*)d_in[7];
  const float* Wp = (const float*)d_in[8];
  const float* bp = (const float*)d_in[9];
  float* out = (float*)d_out;

  char* ws = (char*)d_ws;
  // layout (bytes):
  u16* A_bf = (u16*)(ws + 0);            // 12,582,912 elems -> 25,165,824 B
  u16* W2_bf = (u16*)(ws + 25165824);    // 1,572,864 -> 3,145,728 B
  u16* W3_bf = (u16*)(ws + 28311552);    // 2,359,296 -> 4,718,592 B
  u16* W4_bf = (u16*)(ws + 33030144);    // 3,145,728 -> 6,291,456 B
  u16* a_out = (u16*)(ws + 39321600);    // 16256*1024 bf16
  u16* b_out = (u16*)(ws + 72613888);    // 16128*1024 bf16
  u16* c_out = (u16*)(ws + 105644032);   // 16000*1024 bf16  (end 138,412,032 B)

  cvt_all<<<(N4_TOTAL + 255) / 256, 256, 0, stream>>>(words, W2, W3, W4,
                                                      A_bf, W2_bf, W3_bf, W4_bf);

  // grid: x = tile_n (8, fast-varying -> n-column locality per XCD), y = tile_m, z = branch
  gemm_fused<<<dim3(8, 127, 3), 256, 0, stream>>>(A_bf, W2_bf, W3_bf, W4_bf,
                                                  b2, b3, b4, a_out, b_out, c_out);

  combine_norm<<<dim3(9, BSZ), 256, 0, stream>>>(a_out, b_out, c_out, out);
  sent_head<<<BSZ, 256, 0, stream>>>(sent, Wp, bp, out);
}

// Round 4
// 521.885 us; speedup vs baseline: 1.2993x; 1.1208x over previous
//
#include <hip/hip_runtime.h>
#include <math.h>

typedef unsigned short u16;

#define BSZ 128
#define SEQL 128
#define DIM 768
#define FEAT 1024
#define WORDS_OUT_ELEMS (BSZ * FEAT * 126)  // 16,515,072

typedef __attribute__((ext_vector_type(8))) __bf16 bf16x8;
typedef __attribute__((ext_vector_type(4))) float f32x4;

__device__ __forceinline__ u16 f2bf(float x) {
  unsigned u = __float_as_uint(x);
  u += 0x7FFFu + ((u >> 16) & 1u);
  return (u16)(u >> 16);
}

__device__ __forceinline__ void gld_lds16(const void* g, void* l) {
  __builtin_amdgcn_global_load_lds(
      (const __attribute__((address_space(1))) void*)g,
      (__attribute__((address_space(3))) void*)l, 16, 0, 0);
}

// ---------------- fused fp32 -> bf16 convert ----------------
#define N4_WORDS 3145728
#define N4_W2 393216
#define N4_W3 589824
#define N4_W4 786432
#define N4_TOTAL (N4_WORDS + N4_W2 + N4_W3 + N4_W4)  // 4,915,200

__global__ __launch_bounds__(256) void cvt_all(const float* __restrict__ words,
                                               const float* __restrict__ W2,
                                               const float* __restrict__ W3,
                                               const float* __restrict__ W4,
                                               u16* __restrict__ dA, u16* __restrict__ d2,
                                               u16* __restrict__ d3, u16* __restrict__ d4) {
  int i = blockIdx.x * 256 + threadIdx.x;
  if (i >= N4_TOTAL) return;
  const float* src;
  u16* dst;
  int j = i;
  if (j < N4_WORDS) {
    src = words; dst = dA;
  } else if ((j -= N4_WORDS) < N4_W2) {
    src = W2; dst = d2;
  } else if ((j -= N4_W2) < N4_W3) {
    src = W3; dst = d3;
  } else {
    j -= N4_W3; src = W4; dst = d4;
  }
  float4 v = ((const float4*)src)[j];
  ushort4 o;
  o.x = f2bf(v.x); o.y = f2bf(v.y); o.z = f2bf(v.z); o.w = f2bf(v.w);
  ((ushort4*)dst)[j] = o;
}

// ---------------- conv GEMM, raw-row (no im2col) staging ----------------
// Block = (tile_n, z, b). Stages x[b] rows 0..127 (one 64-d chunk, 16 KB) ONCE,
// serves all K weight slices; branch-z A-fragment for k-slice k = LDS row (l + k).
// W k-slices (16 KB) stream through a 2-deep double buffer (prefetch slice k+1
// during compute of slice k). Barriers per d-chunk: K+1 (vs 2 per 64-MFMA before).
// XOR swizzle (measured conflict-free): global chunk (row r, c) -> LDS slot (r, c^(r&7)).
// C stored PERMUTED within each 64-col wave chunk (stored col frow*4+ni == actual
// col ni*16+frow); combine_norm de-permutes. Rows mg >= Lp are garbage (their
// A-frag rows run off the x tile into the W buffers -- finite) and are not stored.

// stage a 128-row x 64-elem bf16 tile (1024 16B slots, 4 gld_lds per thread)
__device__ __forceinline__ void stage_tile(const u16* __restrict__ gbase, int stride,
                                           u16* __restrict__ ldsbase, int wave, int lane) {
#pragma unroll
  for (int i = 0; i < 4; ++i) {
    int slot = i * 256 + wave * 64 + lane;
    int r = slot >> 3, c = slot & 7;
    const u16* src = gbase + (size_t)r * stride + ((c ^ (r & 7)) * 8);
    unsigned uofs = __builtin_amdgcn_readfirstlane((unsigned)((i * 256 + wave * 64) * 8));
    gld_lds16(src, ldsbase + uofs);
  }
}

template <int K>
__device__ __forceinline__ void run_branch(const u16* __restrict__ A,
                                           const u16* __restrict__ W,
                                           const float* __restrict__ bias,
                                           u16* __restrict__ C,
                                           int b, int tile_n, u16* lds) {
  const int KD = K * 768;
  const int Lp = 129 - K;  // 127,126,125
  const int tid = threadIdx.x;
  const int wave = tid >> 6, lane = tid & 63;
  u16* Xs = lds;               // 1024 slots = 16 KB
  u16* Wb0 = lds + 8192;       // W double buffer, 16 KB each
  u16* Wb1 = lds + 16384;

  const int wm = (wave & 1) * 64;
  const int wn = (wave >> 1) * 64;
  const int frow = lane & 15;
  const int fq = lane >> 4;

  const u16* xg = A + (size_t)b * 128 * 768;
  const u16* wg = W + (size_t)tile_n * 128 * KD;

  f32x4 acc[4][4];
#pragma unroll
  for (int mi = 0; mi < 4; ++mi)
#pragma unroll
    for (int ni = 0; ni < 4; ++ni) acc[mi][ni] = 0.0f;

  for (int d0 = 0; d0 < 768; d0 += 64) {
    stage_tile(xg + d0, 768, Xs, wave, lane);
    stage_tile(wg + d0, KD, Wb0, wave, lane);  // k = 0 slice
    __syncthreads();
#pragma unroll
    for (int k = 0; k < K; ++k) {
      if (k + 1 < K)  // prefetch next W slice into the other buffer
        stage_tile(wg + (k + 1) * 768 + d0, KD, ((k + 1) & 1) ? Wb1 : Wb0, wave, lane);
      const u16* wbuf = (k & 1) ? Wb1 : Wb0;
#pragma unroll
      for (int kc = 0; kc < 2; ++kc) {
        bf16x8 af[4], wf[4];
#pragma unroll
        for (int mi = 0; mi < 4; ++mi) {
          int row = wm + mi * 16 + frow + k;  // k-shifted raw-row read
          af[mi] = *(const bf16x8*)&Xs[(row * 8 + ((kc * 4 + fq) ^ (row & 7))) * 8];
        }
#pragma unroll
        for (int ni = 0; ni < 4; ++ni) {
          int row = wn + ni * 16 + frow;
          wf[ni] = *(const bf16x8*)&wbuf[(row * 8 + ((kc * 4 + fq) ^ (row & 7))) * 8];
        }
#pragma unroll
        for (int mi = 0; mi < 4; ++mi)
#pragma unroll
          for (int ni = 0; ni < 4; ++ni)
            acc[mi][ni] = __builtin_amdgcn_mfma_f32_16x16x32_bf16(af[mi], wf[ni],
                                                                  acc[mi][ni], 0, 0, 0);
      }
      __syncthreads();
    }
  }

  // epilogue: bias + relu, permuted-packed bf16 stores, mask rows >= Lp
  float bv[4];
#pragma unroll
  for (int ni = 0; ni < 4; ++ni) bv[ni] = bias[tile_n * 128 + wn + ni * 16 + frow];
#pragma unroll
  for (int mi = 0; mi < 4; ++mi) {
#pragma unroll
    for (int r = 0; r < 4; ++r) {
      int mg = wm + mi * 16 + fq * 4 + r;
      if (mg < Lp) {
        ushort4 hs;
        hs.x = f2bf(fmaxf(acc[mi][0][r] + bv[0], 0.0f));
        hs.y = f2bf(fmaxf(acc[mi][1][r] + bv[1], 0.0f));
        hs.z = f2bf(fmaxf(acc[mi][2][r] + bv[2], 0.0f));
        hs.w = f2bf(fmaxf(acc[mi][3][r] + bv[3], 0.0f));
        *(ushort4*)(C + (size_t)(b * Lp + mg) * FEAT + tile_n * 128 + wn + frow * 4) = hs;
      }
    }
  }
}

__global__ __launch_bounds__(256) void gemm_fused(const u16* __restrict__ A,
                                                  const u16* __restrict__ W2,
                                                  const u16* __restrict__ W3,
                                                  const u16* __restrict__ W4,
                                                  const float* __restrict__ b2,
                                                  const float* __restrict__ b3,
                                                  const float* __restrict__ b4,
                                                  u16* __restrict__ Ca,
                                                  u16* __restrict__ Cb,
                                                  u16* __restrict__ Cc) {
  __shared__ u16 lds[24576];  // 48 KB: Xs + 2 W buffers
  const int tile_n = blockIdx.x;
  const int z = blockIdx.y;
  const int b = blockIdx.z;
  if (z == 0)
    run_branch<2>(A, W2, b2, Ca, b, tile_n, lds);
  else if (z == 1)
    run_branch<3>(A, W3, b3, Cb, b, tile_n, lds);
  else
    run_branch<4>(A, W4, b4, Cc, b, tile_n, lds);
}

__device__ __forceinline__ float4 load_bf4(const u16* p) {
  uint2 q = *(const uint2*)p;
  float4 r;
  r.x = __uint_as_float((q.x & 0xFFFFu) << 16);
  r.y = __uint_as_float(q.x & 0xFFFF0000u);
  r.z = __uint_as_float((q.y & 0xFFFFu) << 16);
  r.w = __uint_as_float(q.y & 0xFFFF0000u);
  return r;
}

// ---------------- combine (max over branches) + L2 norm over FEAT + transposed write ----------------
// a: (BSZ,127,FEAT) b: (BSZ,126,FEAT) c: (BSZ,125,FEAT), bf16, PERMUTED col layout:
// stored index s (within 64-col chunk) holds actual col (s&3)*16 + (s>>2).
__global__ __launch_bounds__(256) void combine_norm(const u16* __restrict__ a,
                                                    const u16* __restrict__ b,
                                                    const u16* __restrict__ c,
                                                    float* __restrict__ out) {
  __shared__ float comb[14 * 1024];
  __shared__ float red[14 * 4];
  __shared__ float inv[14];
  const int tid = threadIdx.x;
  const int wave = tid >> 6, lane = tid & 63;
  const int l0 = blockIdx.x * 14;
  const int bb = blockIdx.y;
  const int f0 = tid * 4;                       // stored (permuted) index
  const int chunk = tid >> 4, frow = tid & 15;  // de-permute params
  const int fbase = chunk * 64 + frow;          // actual col for ni=0 (then +16 per ni)

  float part[14];
#pragma unroll
  for (int l = 0; l < 14; ++l) {
    int lg = l0 + l;
    float4 v = load_bf4(a + (size_t)(bb * 127 + lg) * 1024 + f0);
    if (lg < 125) {
      float4 vb = load_bf4(b + (size_t)(bb * 126 + lg) * 1024 + f0);
      v.x = fmaxf(v.x, vb.x); v.y = fmaxf(v.y, vb.y);
      v.z = fmaxf(v.z, vb.z); v.w = fmaxf(v.w, vb.w);
    }
    if (lg < 124) {
      float4 vc = load_bf4(c + (size_t)(bb * 125 + lg) * 1024 + f0);
      v.x = fmaxf(v.x, vc.x); v.y = fmaxf(v.y, vc.y);
      v.z = fmaxf(v.z, vc.z); v.w = fmaxf(v.w, vc.w);
    }
    comb[l * 1024 + fbase + 0] = v.x;
    comb[l * 1024 + fbase + 16] = v.y;
    comb[l * 1024 + fbase + 32] = v.z;
    comb[l * 1024 + fbase + 48] = v.w;
    part[l] = v.x * v.x + v.y * v.y + v.z * v.z + v.w * v.w;
  }
#pragma unroll
  for (int l = 0; l < 14; ++l) {
    float v = part[l];
    for (int off = 32; off > 0; off >>= 1) v += __shfl_down(v, off);
    if (lane == 0) red[l * 4 + wave] = v;
  }
  __syncthreads();
  if (tid < 14) {
    float s = red[tid * 4] + red[tid * 4 + 1] + red[tid * 4 + 2] + red[tid * 4 + 3];
    inv[tid] = 1.0f / fmaxf(sqrtf(s), 1e-12f);
  }
  __syncthreads();

  const size_t ob = (size_t)bb * FEAT * 126;
#pragma unroll
  for (int it = 0; it < 4; ++it) {
    int f = tid + it * 256;
    float* po = out + ob + (size_t)f * 126 + l0;
#pragma unroll
    for (int j = 0; j < 7; ++j) {
      float2 w;
      w.x = comb[(2 * j) * 1024 + f] * inv[2 * j];
      w.y = comb[(2 * j + 1) * 1024 + f] * inv[2 * j + 1];
      *(float2*)(po + 2 * j) = w;
    }
  }
}

// ---------------- sentence head: l2norm(se @ Wp^T + bp) ----------------
__global__ __launch_bounds__(256) void sent_head(const float* __restrict__ se,
                                                 const float* __restrict__ Wp,
                                                 const float* __restrict__ bp,
                                                 float* __restrict__ out) {
  __shared__ float srow[768];
  __shared__ float ov[1024];
  __shared__ float red[4];
  const int b = blockIdx.x, tid = threadIdx.x;
  for (int i = tid; i < 768; i += 256) srow[i] = se[b * 768 + i];
  __syncthreads();
  float ss = 0.f;
#pragma unroll
  for (int it = 0; it < 4; ++it) {
    int f = tid + it * 256;
    const float4* w = (const float4*)(Wp + (size_t)f * 768);
    float acc = 0.f;
    for (int j = 0; j < 192; ++j) {
      float4 wv = w[j];
      float4 sv = *(const float4*)&srow[j * 4];
      acc += wv.x * sv.x + wv.y * sv.y + wv.z * sv.z + wv.w * sv.w;
    }
    acc += bp[f];
    ov[f] = acc;
    ss += acc * acc;
  }
  const int lane = tid & 63, wave = tid >> 6;
  for (int off = 32; off > 0; off >>= 1) ss += __shfl_down(ss, off);
  if (lane == 0) red[wave] = ss;
  __syncthreads();
  float tot = red[0] + red[1] + red[2] + red[3];
  float inv = 1.0f / fmaxf(sqrtf(tot), 1e-12f);
  for (int it = 0; it < 4; ++it) {
    int f = tid + it * 256;
    out[WORDS_OUT_ELEMS + (size_t)b * 1024 + f] = ov[f] * inv;
  }
}

extern "C" void kernel_launch(void* const* d_in, const int* in_sizes, int n_in,
                              void* d_out, int out_size, void* d_ws, size_t ws_size,
                              hipStream_t stream) {
  const float* words = (const float*)d_in[0];
  const float* sent = (const float*)d_in[1];
  const float* W2 = (const float*)d_in[2];
  const float* b2 = (const float*)d_in[3];
  const float* W3 = (const float*)d_in[4];
  const float* b3 = (const float*)d_in[5];
  const float* W4 = (const float*)d_in[6];
  const float* b4 = (const float*)d_in[7];
  const float* Wp = (const float*)d_in[8];
  const float* bp = (const float*)d_in[9];
  float* out = (float*)d_out;

  char* ws = (char*)d_ws;
  u16* A_bf = (u16*)(ws + 0);            // 12,582,912 elems -> 25,165,824 B
  u16* W2_bf = (u16*)(ws + 25165824);    // 1,572,864 -> 3,145,728 B
  u16* W3_bf = (u16*)(ws + 28311552);    // 2,359,296 -> 4,718,592 B
  u16* W4_bf = (u16*)(ws + 33030144);    // 3,145,728 -> 6,291,456 B
  u16* a_out = (u16*)(ws + 39321600);    // 16256*1024 bf16
  u16* b_out = (u16*)(ws + 72613888);    // 16128*1024 bf16
  u16* c_out = (u16*)(ws + 105644032);   // 16000*1024 bf16  (end 138,412,032 B)

  cvt_all<<<(N4_TOTAL + 255) / 256, 256, 0, stream>>>(words, W2, W3, W4,
                                                      A_bf, W2_bf, W3_bf, W4_bf);

  // grid: x = tile_n (8 -> fixed XCD per n-column), y = branch, z = batch.
  // The 3 branch-blocks of one (tile_n, b) are 8 apart in linear id -> same XCD,
  // adjacent in dispatch -> x[b] fetched once into that XCD's L2.
  gemm_fused<<<dim3(8, 3, BSZ), 256, 0, stream>>>(A_bf, W2_bf, W3_bf, W4_bf,
                                                  b2, b3, b4, a_out, b_out, c_out);

  combine_norm<<<dim3(9, BSZ), 256, 0, stream>>>(a_out, b_out, c_out, out);
  sent_head<<<BSZ, 256, 0, stream>>>(sent, Wp, bp, out);
}

// Round 5
// 487.257 us; speedup vs baseline: 1.3916x; 1.0711x over previous
//
#include <hip/hip_runtime.h>
#include <math.h>

typedef unsigned short u16;

#define BSZ 128
#define SEQL 128
#define DIM 768
#define FEAT 1024
#define WORDS_OUT_ELEMS (BSZ * FEAT * 126)  // 16,515,072

typedef __attribute__((ext_vector_type(8))) __bf16 bf16x8;
typedef __attribute__((ext_vector_type(4))) float f32x4;

__device__ __forceinline__ u16 f2bf(float x) {
  unsigned u = __float_as_uint(x);
  u += 0x7FFFu + ((u >> 16) & 1u);
  return (u16)(u >> 16);
}

__device__ __forceinline__ void gld_lds16(const void* g, void* l) {
  __builtin_amdgcn_global_load_lds(
      (const __attribute__((address_space(1))) void*)g,
      (__attribute__((address_space(3))) void*)l, 16, 0, 0);
}

// ---------------- fused fp32 -> bf16 convert ----------------
#define N4_WORDS 3145728
#define N4_W2 393216
#define N4_W3 589824
#define N4_W4 786432
#define N4_TOTAL (N4_WORDS + N4_W2 + N4_W3 + N4_W4)  // 4,915,200

__global__ __launch_bounds__(256) void cvt_all(const float* __restrict__ words,
                                               const float* __restrict__ W2,
                                               const float* __restrict__ W3,
                                               const float* __restrict__ W4,
                                               u16* __restrict__ dA, u16* __restrict__ d2,
                                               u16* __restrict__ d3, u16* __restrict__ d4) {
  int i = blockIdx.x * 256 + threadIdx.x;
  if (i >= N4_TOTAL) return;
  const float* src;
  u16* dst;
  int j = i;
  if (j < N4_WORDS) {
    src = words; dst = dA;
  } else if ((j -= N4_WORDS) < N4_W2) {
    src = W2; dst = d2;
  } else if ((j -= N4_W2) < N4_W3) {
    src = W3; dst = d3;
  } else {
    j -= N4_W3; src = W4; dst = d4;
  }
  float4 v = ((const float4*)src)[j];
  ushort4 o;
  o.x = f2bf(v.x); o.y = f2bf(v.y); o.z = f2bf(v.z); o.w = f2bf(v.w);
  ((ushort4*)dst)[j] = o;
}

// ---------------- conv GEMM, raw-row (no im2col) staging ----------------
// (unchanged from R4 -- control. 48.9% MfmaUtil, 0 conflicts, 136 MB fetch.)
__device__ __forceinline__ void stage_tile(const u16* __restrict__ gbase, int stride,
                                           u16* __restrict__ ldsbase, int wave, int lane) {
#pragma unroll
  for (int i = 0; i < 4; ++i) {
    int slot = i * 256 + wave * 64 + lane;
    int r = slot >> 3, c = slot & 7;
    const u16* src = gbase + (size_t)r * stride + ((c ^ (r & 7)) * 8);
    unsigned uofs = __builtin_amdgcn_readfirstlane((unsigned)((i * 256 + wave * 64) * 8));
    gld_lds16(src, ldsbase + uofs);
  }
}

template <int K>
__device__ __forceinline__ void run_branch(const u16* __restrict__ A,
                                           const u16* __restrict__ W,
                                           const float* __restrict__ bias,
                                           u16* __restrict__ C,
                                           int b, int tile_n, u16* lds) {
  const int KD = K * 768;
  const int Lp = 129 - K;  // 127,126,125
  const int tid = threadIdx.x;
  const int wave = tid >> 6, lane = tid & 63;
  u16* Xs = lds;               // 1024 slots = 16 KB
  u16* Wb0 = lds + 8192;       // W double buffer, 16 KB each
  u16* Wb1 = lds + 16384;

  const int wm = (wave & 1) * 64;
  const int wn = (wave >> 1) * 64;
  const int frow = lane & 15;
  const int fq = lane >> 4;

  const u16* xg = A + (size_t)b * 128 * 768;
  const u16* wg = W + (size_t)tile_n * 128 * KD;

  f32x4 acc[4][4];
#pragma unroll
  for (int mi = 0; mi < 4; ++mi)
#pragma unroll
    for (int ni = 0; ni < 4; ++ni) acc[mi][ni] = 0.0f;

  for (int d0 = 0; d0 < 768; d0 += 64) {
    stage_tile(xg + d0, 768, Xs, wave, lane);
    stage_tile(wg + d0, KD, Wb0, wave, lane);  // k = 0 slice
    __syncthreads();
#pragma unroll
    for (int k = 0; k < K; ++k) {
      if (k + 1 < K)  // prefetch next W slice into the other buffer
        stage_tile(wg + (k + 1) * 768 + d0, KD, ((k + 1) & 1) ? Wb1 : Wb0, wave, lane);
      const u16* wbuf = (k & 1) ? Wb1 : Wb0;
#pragma unroll
      for (int kc = 0; kc < 2; ++kc) {
        bf16x8 af[4], wf[4];
#pragma unroll
        for (int mi = 0; mi < 4; ++mi) {
          int row = wm + mi * 16 + frow + k;  // k-shifted raw-row read
          af[mi] = *(const bf16x8*)&Xs[(row * 8 + ((kc * 4 + fq) ^ (row & 7))) * 8];
        }
#pragma unroll
        for (int ni = 0; ni < 4; ++ni) {
          int row = wn + ni * 16 + frow;
          wf[ni] = *(const bf16x8*)&wbuf[(row * 8 + ((kc * 4 + fq) ^ (row & 7))) * 8];
        }
#pragma unroll
        for (int mi = 0; mi < 4; ++mi)
#pragma unroll
          for (int ni = 0; ni < 4; ++ni)
            acc[mi][ni] = __builtin_amdgcn_mfma_f32_16x16x32_bf16(af[mi], wf[ni],
                                                                  acc[mi][ni], 0, 0, 0);
      }
      __syncthreads();
    }
  }

  float bv[4];
#pragma unroll
  for (int ni = 0; ni < 4; ++ni) bv[ni] = bias[tile_n * 128 + wn + ni * 16 + frow];
#pragma unroll
  for (int mi = 0; mi < 4; ++mi) {
#pragma unroll
    for (int r = 0; r < 4; ++r) {
      int mg = wm + mi * 16 + fq * 4 + r;
      if (mg < Lp) {
        ushort4 hs;
        hs.x = f2bf(fmaxf(acc[mi][0][r] + bv[0], 0.0f));
        hs.y = f2bf(fmaxf(acc[mi][1][r] + bv[1], 0.0f));
        hs.z = f2bf(fmaxf(acc[mi][2][r] + bv[2], 0.0f));
        hs.w = f2bf(fmaxf(acc[mi][3][r] + bv[3], 0.0f));
        *(ushort4*)(C + (size_t)(b * Lp + mg) * FEAT + tile_n * 128 + wn + frow * 4) = hs;
      }
    }
  }
}

__global__ __launch_bounds__(256) void gemm_fused(const u16* __restrict__ A,
                                                  const u16* __restrict__ W2,
                                                  const u16* __restrict__ W3,
                                                  const u16* __restrict__ W4,
                                                  const float* __restrict__ b2,
                                                  const float* __restrict__ b3,
                                                  const float* __restrict__ b4,
                                                  u16* __restrict__ Ca,
                                                  u16* __restrict__ Cb,
                                                  u16* __restrict__ Cc) {
  __shared__ u16 lds[24576];  // 48 KB: Xs + 2 W buffers
  const int tile_n = blockIdx.x;
  const int z = blockIdx.y;
  const int b = blockIdx.z;
  if (z == 0)
    run_branch<2>(A, W2, b2, Ca, b, tile_n, lds);
  else if (z == 1)
    run_branch<3>(A, W3, b3, Cb, b, tile_n, lds);
  else
    run_branch<4>(A, W4, b4, Cc, b, tile_n, lds);
}

__device__ __forceinline__ float4 load_bf4(const u16* p) {
  uint2 q = *(const uint2*)p;
  float4 r;
  r.x = __uint_as_float((q.x & 0xFFFFu) << 16);
  r.y = __uint_as_float(q.x & 0xFFFF0000u);
  r.z = __uint_as_float((q.y & 0xFFFFu) << 16);
  r.w = __uint_as_float(q.y & 0xFFFF0000u);
  return r;
}

// ---------------- combine (max over branches) + L2 norm over FEAT + transposed write ----------------
// a: (BSZ,127,FEAT) b: (BSZ,126,FEAT) c: (BSZ,125,FEAT), bf16, PERMUTED col layout
// (stored index s within a 64-col chunk holds actual col (s&3)*16 + (s>>2)).
// v2: l-tile = 16; comb stride 1028 floats (mod 32 = 4 -> column reads 2 lanes/bank = free).
// Write phase: wave covers 16 f-rows/iter (lane = f_off*4 + l_quarter), two float2 per lane,
// contiguous in l -> each store instruction covers 16 rows x 32 B instead of 64 scattered lines.
#define CSTR 1028

__global__ __launch_bounds__(256) void combine_norm(const u16* __restrict__ a,
                                                    const u16* __restrict__ b,
                                                    const u16* __restrict__ c,
                                                    float* __restrict__ out) {
  __shared__ float comb[16 * CSTR];  // 65.8 KB
  __shared__ float red[16 * 4];
  __shared__ float inv[16];
  const int tid = threadIdx.x;
  const int wave = tid >> 6, lane = tid & 63;
  const int l0 = blockIdx.x * 16;
  const int bb = blockIdx.y;
  const int rem = (126 - l0 < 16) ? (126 - l0) : 16;  // 16, last block 14
  const int f0 = tid * 4;                       // stored (permuted) index
  const int chunk = tid >> 4, frow = tid & 15;  // de-permute params
  const int fbase = chunk * 64 + frow;          // actual col for ni=0 (then +16 per ni)

  float part[16];
#pragma unroll
  for (int l = 0; l < 16; ++l) {
    int lg = l0 + l;
    float4 v = make_float4(0.f, 0.f, 0.f, 0.f);
    if (lg < 126) {
      v = load_bf4(a + (size_t)(bb * 127 + lg) * 1024 + f0);
      if (lg < 125) {
        float4 vb = load_bf4(b + (size_t)(bb * 126 + lg) * 1024 + f0);
        v.x = fmaxf(v.x, vb.x); v.y = fmaxf(v.y, vb.y);
        v.z = fmaxf(v.z, vb.z); v.w = fmaxf(v.w, vb.w);
      }
      if (lg < 124) {
        float4 vc = load_bf4(c + (size_t)(bb * 125 + lg) * 1024 + f0);
        v.x = fmaxf(v.x, vc.x); v.y = fmaxf(v.y, vc.y);
        v.z = fmaxf(v.z, vc.z); v.w = fmaxf(v.w, vc.w);
      }
    }
    comb[l * CSTR + fbase + 0] = v.x;
    comb[l * CSTR + fbase + 16] = v.y;
    comb[l * CSTR + fbase + 32] = v.z;
    comb[l * CSTR + fbase + 48] = v.w;
    part[l] = v.x * v.x + v.y * v.y + v.z * v.z + v.w * v.w;
  }
#pragma unroll
  for (int l = 0; l < 16; ++l) {
    float v = part[l];
    for (int off = 32; off > 0; off >>= 1) v += __shfl_down(v, off);
    if (lane == 0) red[l * 4 + wave] = v;
  }
  __syncthreads();
  if (tid < 16) {
    float s = red[tid * 4] + red[tid * 4 + 1] + red[tid * 4 + 2] + red[tid * 4 + 3];
    inv[tid] = 1.0f / fmaxf(sqrtf(s), 1e-12f);
  }
  __syncthreads();

  // write phase: lane -> (l-quarter q, f-row offset fi); wave w covers f in [w*256, w*256+256)
  const int q = lane & 3, fi = lane >> 2;
  const int lb = 4 * q;
  const size_t ob = (size_t)bb * FEAT * 126;
#pragma unroll
  for (int it = 0; it < 16; ++it) {
    int f = wave * 256 + it * 16 + fi;
    if (lb + 2 <= rem) {
      float* po = out + ob + (size_t)f * 126 + l0 + lb;
      float2 w0;
      w0.x = comb[(lb + 0) * CSTR + f] * inv[lb + 0];
      w0.y = comb[(lb + 1) * CSTR + f] * inv[lb + 1];
      *(float2*)po = w0;
      if (lb + 4 <= rem) {
        float2 w1;
        w1.x = comb[(lb + 2) * CSTR + f] * inv[lb + 2];
        w1.y = comb[(lb + 3) * CSTR + f] * inv[lb + 3];
        *(float2*)(po + 2) = w1;
      }
    }
  }
}

// ---------------- sentence head: l2norm(se @ Wp^T + bp) ----------------
__global__ __launch_bounds__(256) void sent_head(const float* __restrict__ se,
                                                 const float* __restrict__ Wp,
                                                 const float* __restrict__ bp,
                                                 float* __restrict__ out) {
  __shared__ float srow[768];
  __shared__ float ov[1024];
  __shared__ float red[4];
  const int b = blockIdx.x, tid = threadIdx.x;
  for (int i = tid; i < 768; i += 256) srow[i] = se[b * 768 + i];
  __syncthreads();
  float ss = 0.f;
#pragma unroll
  for (int it = 0; it < 4; ++it) {
    int f = tid + it * 256;
    const float4* w = (const float4*)(Wp + (size_t)f * 768);
    float acc = 0.f;
    for (int j = 0; j < 192; ++j) {
      float4 wv = w[j];
      float4 sv = *(const float4*)&srow[j * 4];
      acc += wv.x * sv.x + wv.y * sv.y + wv.z * sv.z + wv.w * sv.w;
    }
    acc += bp[f];
    ov[f] = acc;
    ss += acc * acc;
  }
  const int lane = tid & 63, wave = tid >> 6;
  for (int off = 32; off > 0; off >>= 1) ss += __shfl_down(ss, off);
  if (lane == 0) red[wave] = ss;
  __syncthreads();
  float tot = red[0] + red[1] + red[2] + red[3];
  float inv = 1.0f / fmaxf(sqrtf(tot), 1e-12f);
  for (int it = 0; it < 4; ++it) {
    int f = tid + it * 256;
    out[WORDS_OUT_ELEMS + (size_t)b * 1024 + f] = ov[f] * inv;
  }
}

extern "C" void kernel_launch(void* const* d_in, const int* in_sizes, int n_in,
                              void* d_out, int out_size, void* d_ws, size_t ws_size,
                              hipStream_t stream) {
  const float* words = (const float*)d_in[0];
  const float* sent = (const float*)d_in[1];
  const float* W2 = (const float*)d_in[2];
  const float* b2 = (const float*)d_in[3];
  const float* W3 = (const float*)d_in[4];
  const float* b3 = (const float*)d_in[5];
  const float* W4 = (const float*)d_in[6];
  const float* b4 = (const float*)d_in[7];
  const float* Wp = (const float*)d_in[8];
  const float* bp = (const float*)d_in[9];
  float* out = (float*)d_out;

  char* ws = (char*)d_ws;
  u16* A_bf = (u16*)(ws + 0);            // 12,582,912 elems -> 25,165,824 B
  u16* W2_bf = (u16*)(ws + 25165824);    // 1,572,864 -> 3,145,728 B
  u16* W3_bf = (u16*)(ws + 28311552);    // 2,359,296 -> 4,718,592 B
  u16* W4_bf = (u16*)(ws + 33030144);    // 3,145,728 -> 6,291,456 B
  u16* a_out = (u16*)(ws + 39321600);    // 16256*1024 bf16
  u16* b_out = (u16*)(ws + 72613888);    // 16128*1024 bf16
  u16* c_out = (u16*)(ws + 105644032);   // 16000*1024 bf16  (end 138,412,032 B)

  cvt_all<<<(N4_TOTAL + 255) / 256, 256, 0, stream>>>(words, W2, W3, W4,
                                                      A_bf, W2_bf, W3_bf, W4_bf);

  gemm_fused<<<dim3(8, 3, BSZ), 256, 0, stream>>>(A_bf, W2_bf, W3_bf, W4_bf,
                                                  b2, b3, b4, a_out, b_out, c_out);

  combine_norm<<<dim3(8, BSZ), 256, 0, stream>>>(a_out, b_out, c_out, out);
  sent_head<<<BSZ, 256, 0, stream>>>(sent, Wp, bp, out);
}